// Round 7
// baseline (141.818 us; speedup 1.0000x reference)
//
#include <hip/hip_runtime.h>
#include <math.h>

// NLM S=21, 256x256x3, reflect padding. Round 7:
// - software-pipelined rounds: h(o+1) -> ping buffer AND v(o) <- pong buffer in
//   the SAME barrier segment (1 barrier/offset, h-LDS overlaps v-VALU)
// - 104 h-tasks (16-wide chunks) on waves 0-1 (52 lanes each, symmetric);
//   waves 2-3 v-only; cross-block overlap (4 blk/CU) absorbs imbalance
// - fp16 staging, fdot2 vertical sums, NG=16, direct-store partials (as R6)

#define IMG 256
#define NPIX (IMG * IMG)
#define TILE 32
#define GR 52      // TILE + 20 (window-grid dim)
#define YD 72      // TILE + 40 (Y region dim)
#define YSTR 78    // Yreg row stride in halves (39 dwords, odd -> full bank spread)
#define RSTR 54    // hs row stride in halves (27 dwords, odd -> full bank spread)
#define NOFF 441
#define NG 16

typedef __attribute__((ext_vector_type(4))) _Float16 half4;
typedef __attribute__((ext_vector_type(2))) _Float16 half2_t;

#if __has_builtin(__builtin_amdgcn_fdot2)
#define FDOT2(a, b, c) __builtin_amdgcn_fdot2((a), (b), (c), false)
#else
#define FDOT2(a, b, c) ((c) + (float)(a).x * (float)(b).x + (float)(a).y * (float)(b).y)
#endif

__device__ __forceinline__ int refl(int t) {
    t = t < 0 ? -t : t;             // valid for t in [-255, 510]
    return t > 255 ? 510 - t : t;
}

template <bool DIRECT>
__global__ __launch_bounds__(256, 4)
void nlm_main(const float* __restrict__ rgb, const float* __restrict__ hptr,
              float4* __restrict__ partials)
{
    __shared__ _Float16 Yreg[YD][YSTR];          // 11232 B (clipped luminance, fp16)
    __shared__ _Float16 Creg4[GR][GR][4];        // 21632 B (RGBX taps at window grid)
    __shared__ _Float16 hsAB[2][TILE][RSTR];     //  6912 B (h-sums, fp16, ping-pong)
    __shared__ unsigned char cjTab[21][GR];      //  1092 B (col refl maps per dv; [10]=identity)
    // total 40868 B -> rounds to 40960 -> 4 blocks/CU

    const int tid = threadIdx.x;
    const int tj = ((int)blockIdx.x & 7) * TILE;
    const int ti = ((int)blockIdx.x >> 3) * TILE;

    const int Ybi = min(max(ti - 20, 0), IMG - YD);
    const int Ybj = min(max(tj - 20, 0), IMG - YD);
    const bool interior = (ti >= 20) && (ti + 51 <= 255) && (tj >= 20) && (tj + 51 <= 255);

    // ---- stage Y (clipped luminance, fp16) ----
    for (int idx = tid; idx < YD * YD; idx += 256) {
        int a = idx / YD, b = idx - a * YD;
        int g = (Ybi + a) * IMG + (Ybj + b);
        float r  = fminf(fmaxf(rgb[g], 0.f), 1.f);
        float gg = fminf(fmaxf(rgb[NPIX + g], 0.f), 1.f);
        float bb = fminf(fmaxf(rgb[2 * NPIX + g], 0.f), 1.f);
        Yreg[a][b] = (_Float16)(0.299f * r + 0.587f * gg + 0.114f * bb);
    }
    // ---- stage RGBX taps at window-grid coords (UNclipped rgb) ----
    for (int idx = tid; idx < GR * GR; idx += 256) {
        int t = idx / GR, b = idx - t * GR;
        int g = refl(ti - 10 + t) * IMG + refl(tj - 10 + b);
        half4 c;
        c.x = (_Float16)rgb[g];
        c.y = (_Float16)rgb[NPIX + g];
        c.z = (_Float16)rgb[2 * NPIX + g];
        c.w = (_Float16)0.f;
        *(half4*)&Creg4[t][b][0] = c;
    }
    // ---- col refl maps for all dv (edge tiles; [10] also = identity y0 map) ----
    if (!interior) {
        for (int idx = tid; idx < 21 * GR; idx += 256) {
            int d = idx / GR, c = idx - d * GR;
            cjTab[d][c] = (unsigned char)(refl(refl(tj - 10 + c) + (d - 10)) - Ybj);
        }
    }

    const float hv = fmaxf(hptr[0], 0.f);
    const float negI = -1.0f / (hv + 1e-8f);

    // h decomposition: wave 0 -> chunk 0, wave 1 -> chunk 1; lanes 0..51 active
    const int hl = tid & 63;                 // row t (valid < 52)
    const int hw = tid >> 6;                 // wave id
    const bool hactive = (hl < GR) && (hw < 2);
    const int c0 = hw * 16;

    // v decomposition
    const int pb = tid & 31;                 // pixel col
    const int s4 = (tid >> 5) << 2;          // strip start row (0,4,...,28)
    float aR[4], aG[4], aB[4], aW[4];
    #pragma unroll
    for (int k = 0; k < 4; ++k) { aR[k] = 0.f; aG[k] = 0.f; aB[k] = 0.f; aW[k] = 0.f; }

    half2_t one; one.x = (_Float16)1.f; one.y = (_Float16)1.f;

    auto do_h = [&](int du, int dv, int buf) {
        if (!hactive) return;
        const int t = hl;
        _Float16* hsb = &hsAB[buf][0][0];
        float f[36];
        if (interior) {
            const _Float16* y0p = &Yreg[t + 10][c0 + 10];
            const _Float16* y1p = &Yreg[t + 10 + du][c0 + 10 + dv];
            if ((dv & 1) == 0) {
                const half2_t* q0 = (const half2_t*)y0p;
                const half2_t* q1 = (const half2_t*)y1p;
                #pragma unroll
                for (int i = 0; i < 18; ++i) {
                    half2_t d2 = q0[i] - q1[i];
                    half2_t p2 = d2 * d2;
                    f[2 * i]     = (float)p2.x;
                    f[2 * i + 1] = (float)p2.y;
                }
            } else {
                const half2_t* q0 = (const half2_t*)y0p;
                const half2_t* q1 = (const half2_t*)(y1p - 1);
                half2_t prev = q1[0];
                #pragma unroll
                for (int i = 0; i < 18; ++i) {
                    half2_t cur = q1[i + 1];
                    half2_t b; b.x = prev.y; b.y = cur.x;
                    half2_t d2 = q0[i] - b;
                    half2_t p2 = d2 * d2;
                    f[2 * i]     = (float)p2.x;
                    f[2 * i + 1] = (float)p2.y;
                    prev = cur;
                }
            }
        } else {
            const unsigned char* cj0 = &cjTab[10][0];
            const unsigned char* cj1 = &cjTab[dv + 10][0];
            const _Float16* Y0row = &Yreg[refl(ti - 10 + t) - Ybi][0];
            const _Float16* Y1row = &Yreg[refl(refl(ti - 10 + t) + du) - Ybi][0];
            #pragma unroll
            for (int j = 0; j < 36; ++j) {
                int c = c0 + j;
                float d = (float)Y0row[cj0[c]] - (float)Y1row[cj1[c]];
                f[j] = d * d;
            }
        }
        float s = f[0];
        #pragma unroll
        for (int j = 1; j < 21; ++j) s += f[j];
        hsb[c0 * RSTR + t] = (_Float16)s;
        #pragma unroll
        for (int k = 1; k < 16; ++k) {
            s += f[20 + k] - f[k - 1];
            hsb[(c0 + k) * RSTR + t] = (_Float16)s;
        }
    };

    auto do_v = [&](int du, int dv, int buf) {
        const half2_t* col = (const half2_t*)&hsAB[buf][pb][s4];  // s4,RSTR even -> 4B aligned

        half2_t v[12];
        #pragma unroll
        for (int i = 0; i < 12; ++i) v[i] = col[i];
        float vs = 0.f;
        #pragma unroll
        for (int i = 0; i < 10; ++i) vs = FDOT2(v[i], one, vs);
        vs += (float)v[10].x;

        float vss[4];
        vss[0] = vs;
        vss[1] = vss[0] + (float)v[10].y - (float)v[0].x;
        vss[2] = vss[1] + (float)v[11].x - (float)v[0].y;
        vss[3] = vss[2] + (float)v[11].y - (float)v[1].x;

        const int cr = 10 + du;
        const int cc = pb + 10 + dv;
        #pragma unroll
        for (int k = 0; k < 4; ++k) {
            float dist = sqrtf(fmaxf(vss[k], 0.f));
            float w = __expf(dist * negI);
            half4 c = *(const half4*)&Creg4[s4 + k + cr][cc][0];
            aW[k] += w;
            aR[k] += w * (float)c.x;
            aG[k] += w * (float)c.y;
            aB[k] += w * (float)c.z;
        }
    };

    // ---- software-pipelined offset loop ----
    const int y = (int)blockIdx.y;
    const int cnt = (440 - y) / NG + 1;      // number of offsets for this group
    int du = -10, dv = y - 10;               // y < 16 -> first offset row is -10

    __syncthreads();                         // staging complete
    do_h(du, dv, 0);                         // prologue: produce offset 0

    for (int k = 0; k < cnt; ++k) {
        int du2 = du, dv2 = dv + NG;
        if (dv2 > 10) { dv2 -= 21; du2 += 1; }

        __syncthreads();                     // h(o_k) visible; v(o_{k-1}) done
        if (k + 1 < cnt) do_h(du2, dv2, (k + 1) & 1);
        do_v(du, dv, k & 1);

        du = du2; dv = dv2;
    }

    // ---- epilogue: one float4 per pixel ----
    #pragma unroll
    for (int k = 0; k < 4; ++k) {
        int gpix = (ti + s4 + k) * IMG + (tj + pb);
        float4 st = make_float4(aR[k], aG[k], aB[k], aW[k]);
        if (DIRECT) {
            partials[(size_t)blockIdx.y * NPIX + gpix] = st;
        } else {
            float* p = (float*)&partials[gpix];
            atomicAdd(p + 0, st.x);
            atomicAdd(p + 1, st.y);
            atomicAdd(p + 2, st.z);
            atomicAdd(p + 3, st.w);
        }
    }
}

template <int NGT>
__global__ __launch_bounds__(256)
void nlm_finalize(const float4* __restrict__ partials, float* __restrict__ out)
{
    int idx = blockIdx.x * blockDim.x + threadIdx.x;
    float r = 0.f, g = 0.f, b = 0.f, w = 0.f;
    #pragma unroll
    for (int gg = 0; gg < NGT; ++gg) {
        float4 p = partials[(size_t)gg * NPIX + idx];
        r += p.x; g += p.y; b += p.z; w += p.w;
    }
    float inv = 1.0f / w;   // sum(w) >= 1 (self offset contributes exp(0))
    out[idx]            = fminf(fmaxf(r * inv, 0.f), 1.f);
    out[NPIX + idx]     = fminf(fmaxf(g * inv, 0.f), 1.f);
    out[2 * NPIX + idx] = fminf(fmaxf(b * inv, 0.f), 1.f);
}

extern "C" void kernel_launch(void* const* d_in, const int* in_sizes, int n_in,
                              void* d_out, int out_size, void* d_ws, size_t ws_size,
                              hipStream_t stream) {
    (void)in_sizes; (void)n_in; (void)out_size;
    const float* rgb  = (const float*)d_in[0];
    const float* hptr = (const float*)d_in[1];
    float* out = (float*)d_out;
    float4* partials = (float4*)d_ws;

    const bool direct = ws_size >= (size_t)NG * NPIX * sizeof(float4);  // 16.8 MB
    dim3 grid(64, NG);
    if (direct) {
        nlm_main<true><<<grid, 256, 0, stream>>>(rgb, hptr, partials);
        nlm_finalize<NG><<<NPIX / 256, 256, 0, stream>>>(partials, out);
    } else {
        (void)hipMemsetAsync(partials, 0, (size_t)NPIX * sizeof(float4), stream);
        nlm_main<false><<<grid, 256, 0, stream>>>(rgb, hptr, partials);
        nlm_finalize<1><<<NPIX / 256, 256, 0, stream>>>(partials, out);
    }
}